// Round 2
// baseline (578.748 us; speedup 1.0000x reference)
//
#include <hip/hip_runtime.h>
#include <hip/hip_bf16.h>
#include <cstdint>
#include <cstddef>

// CausalSelfAttention: B=4, T=2048, C=1024, H=16, hs=64 (fp32 in/out, bf16 MFMA compute)
//
// Pipeline: x->bf16 | W^T bf16 | GEMM1 (qkv) | V-transpose | flash attn | GEMM2
//
// Workspace layout (96 MiB):
//   [0,16M)   x_bf16 (GEMM1 input), then Vt[b][h][64][2048] (attn input)
//   [16M,22M) W_attn^T bf16
//   [24M,26M) W_proj^T bf16
//   [32M,80M) qkv bf16      (8192 x 3072)
//   [80M,96M) y bf16        (8192 x 1024)

typedef unsigned short ushort_t;
typedef __attribute__((ext_vector_type(8))) short short8;
typedef __attribute__((ext_vector_type(4))) float f32x4;

#define AS1 __attribute__((address_space(1)))
#define AS3 __attribute__((address_space(3)))

#if __has_builtin(__builtin_amdgcn_exp2f)
#define EXP2(x) __builtin_amdgcn_exp2f(x)
#else
#define EXP2(x) exp2f(x)
#endif

__device__ __forceinline__ ushort_t f2bf(float f) {
  union { float f; unsigned u; } c; c.f = f;
  unsigned u = c.u;
  return (ushort_t)((u + 0x7FFFu + ((u >> 16) & 1u)) >> 16);  // RNE
}

// v_cvt_pk_bf16_f32: lo16 = bf16(a), hi16 = bf16(b)
__device__ __forceinline__ unsigned cvt_pk_bf16(float a, float b) {
  unsigned r;
  asm("v_cvt_pk_bf16_f32 %0, %1, %2" : "=v"(r) : "v"(a), "v"(b));
  return r;
}

// ---------------- fp32 -> bf16 elementwise (8 elems/thread) ----------------
__global__ __launch_bounds__(256) void k_f32_to_bf16(const float* __restrict__ in,
                                                     ushort_t* __restrict__ out) {
  const size_t i = ((size_t)blockIdx.x * 256 + threadIdx.x) * 8;
  f32x4 a = *(const f32x4*)(in + i);
  f32x4 b = *(const f32x4*)(in + i + 4);
  short8 o;
  o[0] = (short)f2bf(a[0]); o[1] = (short)f2bf(a[1]);
  o[2] = (short)f2bf(a[2]); o[3] = (short)f2bf(a[3]);
  o[4] = (short)f2bf(b[0]); o[5] = (short)f2bf(b[1]);
  o[6] = (short)f2bf(b[2]); o[7] = (short)f2bf(b[3]);
  *(short8*)(out + i) = o;
}

// ------------- fp32 (R x C) -> bf16 transposed (C x R), LDS-tiled ----------
__global__ __launch_bounds__(256) void k_transpose_bf16(const float* __restrict__ in,
                                                        ushort_t* __restrict__ out,
                                                        int R, int C) {
  __shared__ float tile[32][33];
  const int tx = threadIdx.x & 31, ty = threadIdx.x >> 5;  // 32x8
  const int c0 = blockIdx.x * 32, r0 = blockIdx.y * 32;
#pragma unroll
  for (int i = 0; i < 32; i += 8)
    tile[ty + i][tx] = in[(size_t)(r0 + ty + i) * C + c0 + tx];
  __syncthreads();
#pragma unroll
  for (int i = 0; i < 32; i += 8)
    out[(size_t)(c0 + ty + i) * R + r0 + tx] = f2bf(tile[tx][ty + i]);
}

// ---- V transpose: qkv V-section (t-major) -> Vt[b][h][d][t] (key-major) ----
__global__ __launch_bounds__(256) void k_vt(const ushort_t* __restrict__ qkv,
                                            ushort_t* __restrict__ vt) {
  __shared__ ushort_t tl[64][72];
  const int T = 2048, C3 = 3072;
  const int t0 = blockIdx.x * 64, h = blockIdx.y, b = blockIdx.z;
  const int r = threadIdx.x >> 4;         // 0..15
  const int c4 = (threadIdx.x & 15) * 4;  // 0..60
  const ushort_t* src = qkv + (size_t)(b * T + t0) * C3 + 2048 + h * 64;
#pragma unroll
  for (int p = 0; p < 4; p++) {
    const int row = p * 16 + r;
    *(short4*)&tl[row][c4] = *(const short4*)(src + (size_t)row * C3 + c4);
  }
  __syncthreads();
  ushort_t* dst = vt + (size_t)((b * 16 + h) * 64) * T + t0;
#pragma unroll
  for (int p = 0; p < 4; p++) {
    const int d = p * 16 + r;
    short4 o;
    o.x = (short)tl[c4 + 0][d];
    o.y = (short)tl[c4 + 1][d];
    o.z = (short)tl[c4 + 2][d];
    o.w = (short)tl[c4 + 3][d];
    *(short4*)(dst + (size_t)d * T + c4) = o;
  }
}

// ---------------- bf16 GEMM: C[M,N] = A[M,K] * Bt[N,K]^T -------------------
template <bool OUT_BF16>
__global__ __launch_bounds__(256) void k_gemm_bt(const ushort_t* __restrict__ A,
                                                 const ushort_t* __restrict__ Bt,
                                                 void* __restrict__ Cout,
                                                 int N, int K) {
  __shared__ ushort_t As[128 * 64];
  __shared__ ushort_t Bs[128 * 64];
  const int tid = threadIdx.x;
  const int wave = tid >> 6, lane = tid & 63;
  const int c = lane & 15, g = lane >> 4;
  const int wm = wave >> 1, wn = wave & 1;
  const int bx = blockIdx.x, by = blockIdx.y;

  f32x4 acc[4][4];
#pragma unroll
  for (int m = 0; m < 4; m++)
#pragma unroll
    for (int n = 0; n < 4; n++) acc[m][n] = (f32x4){0.f, 0.f, 0.f, 0.f};

  for (int k0 = 0; k0 < K; k0 += 64) {
#pragma unroll
    for (int i = 0; i < 4; i++) {
      const int flat = i * 256 + tid;
      const ushort_t* srcA = A + (size_t)(by * 128 + (flat >> 3)) * K + k0 + (flat & 7) * 8;
      const ushort_t* srcB = Bt + (size_t)(bx * 128 + (flat >> 3)) * K + k0 + (flat & 7) * 8;
      const int ldsoff = (i * 256 + wave * 64) * 16;
      __builtin_amdgcn_global_load_lds((const AS1 void*)srcA,
                                       (AS3 void*)((char*)As + ldsoff), 16, 0, 0);
      __builtin_amdgcn_global_load_lds((const AS1 void*)srcB,
                                       (AS3 void*)((char*)Bs + ldsoff), 16, 0, 0);
    }
    __syncthreads();
#pragma unroll
    for (int kk = 0; kk < 2; kk++) {
      short8 af[4], bfr[4];
#pragma unroll
      for (int m = 0; m < 4; m++)
        af[m] = *(const short8*)(As + (wm * 64 + m * 16 + c) * 64 + kk * 32 + g * 8);
#pragma unroll
      for (int n = 0; n < 4; n++)
        bfr[n] = *(const short8*)(Bs + (wn * 64 + n * 16 + c) * 64 + kk * 32 + g * 8);
#pragma unroll
      for (int m = 0; m < 4; m++)
#pragma unroll
        for (int n = 0; n < 4; n++)
          acc[m][n] = __builtin_amdgcn_mfma_f32_16x16x32_bf16(af[m], bfr[n], acc[m][n], 0, 0, 0);
    }
    __syncthreads();
  }

#pragma unroll
  for (int m = 0; m < 4; m++)
#pragma unroll
    for (int n = 0; n < 4; n++) {
      const int col = bx * 128 + wn * 64 + n * 16 + c;
#pragma unroll
      for (int r = 0; r < 4; r++) {
        const int row = by * 128 + wm * 64 + m * 16 + g * 4 + r;
        if (OUT_BF16)
          ((ushort_t*)Cout)[(size_t)row * N + col] = f2bf(acc[m][n][r]);
        else
          ((float*)Cout)[(size_t)row * N + col] = acc[m][n][r];
      }
    }
}

// ---------------- flash attention, causal, hs=64 ----------------------------
// Grid (T/64, H, B), 4 waves/block, wave owns 16 q-rows; 64-key tiles.
// S^T = K*Q^T (q = lane&15), y^T = V^T*P^T (q = lane&15): softmax/rescale
// shuffle-free. V read from pre-transposed Vt (coalesced short8).
__global__ __launch_bounds__(256) void k_attn(const ushort_t* __restrict__ qkv,
                                              const ushort_t* __restrict__ vt,
                                              ushort_t* __restrict__ y) {
  const int T = 2048, C3 = 3072, Cc = 1024;
  const int tid = threadIdx.x;
  const int wave = tid >> 6, lane = tid & 63;
  const int c = lane & 15, g = lane >> 4;
  const int b = blockIdx.z, h = blockIdx.y;
  // light/heavy interleave over causal workload
  const int bx = blockIdx.x;
  const int qi = (bx & 1) ? (31 - (bx >> 1)) : (bx >> 1);
  const int qbase = qi * 64 + wave * 16;

  const size_t base = (size_t)b * T * C3 + h * 64;
  const ushort_t* Q = qkv + base;
  const ushort_t* Kp = qkv + base + 1024;
  const ushort_t* Vt = vt + (size_t)((b * 16 + h) * 64) * T;

  const float KS = 0.125f * 1.44269504f;  // scale * log2(e), folded into exp arg
  const float THR = 11.5415f;             // defer-max threshold (8 nats in exp2 units)

  // Q^T B-fragment: lane holds Q[qbase+c][kk*32 + g*8 + r]
  short8 qf0, qf1;
  {
    const ushort_t* qp = Q + (size_t)(qbase + c) * C3 + g * 8;
    qf0 = *(const short8*)qp;
    qf1 = *(const short8*)(qp + 32);
  }

  f32x4 yacc[4];
#pragma unroll
  for (int dc = 0; dc < 4; dc++) yacc[dc] = (f32x4){0.f, 0.f, 0.f, 0.f};
  float m = -3.0e38f, ssum = 0.f;
  const int q = qbase + c;
  const int shamt = (g & 2) * 8;  // pf lo/hi word select

  const int nk = qbase + 16;  // keys needed: 0..qbase+15
  for (int kb = 0; kb < nk; kb += 64) {
    // --- QK^T: 64 keys, K A-fragments direct from global (L2-resident) ---
    const ushort_t* kp = Kp + (size_t)(kb + c) * C3 + g * 8;
    short8 kf[4][2];
#pragma unroll
    for (int sub = 0; sub < 4; sub++) {
#pragma unroll
      for (int kk = 0; kk < 2; kk++)
        kf[sub][kk] = *(const short8*)(kp + (size_t)sub * 16 * C3 + kk * 32);
    }
    f32x4 s[4];
    const f32x4 z = (f32x4){0.f, 0.f, 0.f, 0.f};
    __builtin_amdgcn_s_setprio(1);
#pragma unroll
    for (int sub = 0; sub < 4; sub++) {
      s[sub] = __builtin_amdgcn_mfma_f32_16x16x32_bf16(kf[sub][0], qf0, z, 0, 0, 0);
      s[sub] = __builtin_amdgcn_mfma_f32_16x16x32_bf16(kf[sub][1], qf1, s[sub], 0, 0, 0);
    }
    __builtin_amdgcn_s_setprio(0);

    // lane holds S_raw[q][key = kb + sub*16 + g*4 + r] in s[sub][r]
    float sv[16];
#pragma unroll
    for (int sub = 0; sub < 4; sub++)
#pragma unroll
      for (int r = 0; r < 4; r++) sv[sub * 4 + r] = s[sub][r];

    if (kb + 63 > qbase) {  // diagonal tile: causal mask (wave-uniform branch)
#pragma unroll
      for (int j = 0; j < 16; j++) {
        const int key = kb + (j >> 2) * 16 + g * 4 + (j & 3);
        if (key > q) sv[j] = -3.0e38f;
      }
    }

    // --- online softmax, q = lane&15 (replicated over 4 groups) ---
    float tm = fmaxf(fmaxf(sv[0], sv[1]), sv[2]);
#pragma unroll
    for (int j = 3; j < 16; j += 2) tm = fmaxf(tm, fmaxf(sv[j], sv[j + 1]));
    tm = fmaxf(tm, sv[15]);
    tm = fmaxf(tm, __shfl_xor(tm, 16));
    tm = fmaxf(tm, __shfl_xor(tm, 32));
    const float cand = tm * KS;

    if (__any(cand > m + THR)) {  // rescale path (defer-max, T13)
      const float mnew = fmaxf(m, cand);
      const float alpha = EXP2(m - mnew);
      ssum *= alpha;
#pragma unroll
      for (int dc = 0; dc < 4; dc++)
#pragma unroll
        for (int r = 0; r < 4; r++) yacc[dc][r] *= alpha;
      m = mnew;
    }

    float p[16], ts = 0.f;
#pragma unroll
    for (int j = 0; j < 16; j++) {
      p[j] = EXP2(__builtin_fmaf(sv[j], KS, -m));
      ts += p[j];
    }
    ts += __shfl_xor(ts, 16);
    ts += __shfl_xor(ts, 32);
    ssum += ts;

    // pack P to bf16 pairs: pk[hh][jr] = (p[8hh+jr], p[8hh+4+jr])
    unsigned pk[2][4];
#pragma unroll
    for (int jr = 0; jr < 4; jr++) {
      pk[0][jr] = cvt_pk_bf16(p[jr], p[4 + jr]);
      pk[1][jr] = cvt_pk_bf16(p[8 + jr], p[12 + jr]);
    }

    // --- PV: two 32-key halves ---
#pragma unroll
    for (int hh = 0; hh < 2; hh++) {
      // P^T B-fragment: pf[r] = P[q=c][key = kb + hh*32 + g*8 + r]
      short8 pf;
#pragma unroll
      for (int r = 0; r < 8; r++) {
        const int G = (2 * g + (r >> 2)) & 3;
        const unsigned w = __shfl(pk[hh][r & 3], c | (G << 4), 64);
        pf[r] = (short)(ushort_t)(w >> shamt);
      }
      // V^T A-fragments from Vt (coalesced short8 loads)
      short8 vf[4];
#pragma unroll
      for (int dc = 0; dc < 4; dc++)
        vf[dc] = *(const short8*)(Vt + (size_t)(dc * 16 + c) * T + kb + hh * 32 + g * 8);
      __builtin_amdgcn_s_setprio(1);
#pragma unroll
      for (int dc = 0; dc < 4; dc++)
        yacc[dc] = __builtin_amdgcn_mfma_f32_16x16x32_bf16(vf[dc], pf, yacc[dc], 0, 0, 0);
      __builtin_amdgcn_s_setprio(0);
    }
  }

  // --- normalize + packed store (4x short4 per lane) ---
  const float inv = 1.0f / ssum;
  ushort_t* yp = y + (size_t)(b * T + q) * Cc + h * 64;
#pragma unroll
  for (int dc = 0; dc < 4; dc++) {
    short4 o;
    o.x = (short)f2bf(yacc[dc][0] * inv);
    o.y = (short)f2bf(yacc[dc][1] * inv);
    o.z = (short)f2bf(yacc[dc][2] * inv);
    o.w = (short)f2bf(yacc[dc][3] * inv);
    *(short4*)(yp + dc * 16 + g * 4) = o;
  }
}

// ---------------------------------------------------------------------------
extern "C" void kernel_launch(void* const* d_in, const int* in_sizes, int n_in,
                              void* d_out, int out_size, void* d_ws, size_t ws_size,
                              hipStream_t stream) {
  const float* x = (const float*)d_in[0];     // (4, 2048, 1024)
  const float* Wat = (const float*)d_in[1];   // (1024, 3072)
  const float* Wpr = (const float*)d_in[2];   // (1024, 1024)
  float* out = (float*)d_out;                 // (4, 2048, 1024)

  const int T = 2048, B = 4, H = 16, Cc = 1024;
  const int M = B * T;  // 8192

  char* ws = (char*)d_ws;
  const size_t MB = 1024 * 1024;
  ushort_t* xb = (ushort_t*)ws;                 // 16 MB (x_bf16, then Vt)
  ushort_t* wat = (ushort_t*)(ws + 16 * MB);    // 6 MB
  ushort_t* wpt = (ushort_t*)(ws + 24 * MB);    // 2 MB
  ushort_t* qkv = (ushort_t*)(ws + 32 * MB);    // 48 MB
  ushort_t* yb = (ushort_t*)(ws + 80 * MB);     // 16 MB
  ushort_t* vtb = xb;                           // reuse after GEMM1

  // 1. convert inputs to bf16 (weights transposed to [N][K])
  k_f32_to_bf16<<<dim3((M * Cc) / (8 * 256)), 256, 0, stream>>>(x, xb);
  k_transpose_bf16<<<dim3(3072 / 32, 1024 / 32), 256, 0, stream>>>(Wat, wat, 1024, 3072);
  k_transpose_bf16<<<dim3(1024 / 32, 1024 / 32), 256, 0, stream>>>(Wpr, wpt, 1024, 1024);

  // 2. qkv = x @ W_attn   (8192 x 3072)
  k_gemm_bt<true><<<dim3(3072 / 128, M / 128), 256, 0, stream>>>(xb, wat, qkv, 3072, 1024);

  // 3. V -> Vt[b][h][d][t]  (xb region is dead now)
  k_vt<<<dim3(T / 64, H, B), 256, 0, stream>>>(qkv, vtb);

  // 4. causal flash attention -> y (8192 x 1024 bf16)
  k_attn<<<dim3(T / 64, H, B), 256, 0, stream>>>(qkv, vtb, yb);

  // 5. out = y @ W_proj   (8192 x 1024, fp32)
  k_gemm_bt<false><<<dim3(1024 / 128, M / 128), 256, 0, stream>>>(yb, wpt, out, 1024, 1024);
}

// Round 3
// 263.430 us; speedup vs baseline: 2.1970x; 2.1970x over previous
//
#include <hip/hip_runtime.h>
#include <hip/hip_bf16.h>
#include <cstdint>
#include <cstddef>

// CausalSelfAttention: B=4, T=2048, C=1024, H=16, hs=64 (fp32 in/out, bf16 MFMA compute)
//
// Pipeline: x->bf16 | W^T bf16 | GEMM1 (qkv) | V-transpose | flash attn | GEMM2
//
// Workspace layout (96 MiB):
//   [0,16M)   x_bf16 (GEMM1 input), then Vt[b][h][64][2048] (attn input)
//   [16M,22M) W_attn^T bf16
//   [24M,26M) W_proj^T bf16
//   [32M,80M) qkv bf16      (8192 x 3072)
//   [80M,96M) y bf16        (8192 x 1024)

typedef unsigned short ushort_t;
typedef __attribute__((ext_vector_type(8))) short short8;
typedef __attribute__((ext_vector_type(4))) float f32x4;

#define AS1 __attribute__((address_space(1)))
#define AS3 __attribute__((address_space(3)))

#if __has_builtin(__builtin_amdgcn_exp2f)
#define EXP2(x) __builtin_amdgcn_exp2f(x)
#else
#define EXP2(x) exp2f(x)
#endif

__device__ __forceinline__ ushort_t f2bf(float f) {
  union { float f; unsigned u; } c; c.f = f;
  unsigned u = c.u;
  return (ushort_t)((u + 0x7FFFu + ((u >> 16) & 1u)) >> 16);  // RNE
}

// v_cvt_pk_bf16_f32: lo16 = bf16(a), hi16 = bf16(b)
__device__ __forceinline__ unsigned cvt_pk_bf16(float a, float b) {
  unsigned r;
  asm("v_cvt_pk_bf16_f32 %0, %1, %2" : "=v"(r) : "v"(a), "v"(b));
  return r;
}

// ---------------- fp32 -> bf16 elementwise (8 elems/thread) ----------------
__global__ __launch_bounds__(256) void k_f32_to_bf16(const float* __restrict__ in,
                                                     ushort_t* __restrict__ out) {
  const size_t i = ((size_t)blockIdx.x * 256 + threadIdx.x) * 8;
  f32x4 a = *(const f32x4*)(in + i);
  f32x4 b = *(const f32x4*)(in + i + 4);
  short8 o;
  o[0] = (short)f2bf(a[0]); o[1] = (short)f2bf(a[1]);
  o[2] = (short)f2bf(a[2]); o[3] = (short)f2bf(a[3]);
  o[4] = (short)f2bf(b[0]); o[5] = (short)f2bf(b[1]);
  o[6] = (short)f2bf(b[2]); o[7] = (short)f2bf(b[3]);
  *(short8*)(out + i) = o;
}

// ------------- fp32 (R x C) -> bf16 transposed (C x R), LDS-tiled ----------
__global__ __launch_bounds__(256) void k_transpose_bf16(const float* __restrict__ in,
                                                        ushort_t* __restrict__ out,
                                                        int R, int C) {
  __shared__ float tile[32][33];
  const int tx = threadIdx.x & 31, ty = threadIdx.x >> 5;  // 32x8
  const int c0 = blockIdx.x * 32, r0 = blockIdx.y * 32;
#pragma unroll
  for (int i = 0; i < 32; i += 8)
    tile[ty + i][tx] = in[(size_t)(r0 + ty + i) * C + c0 + tx];
  __syncthreads();
#pragma unroll
  for (int i = 0; i < 32; i += 8)
    out[(size_t)(c0 + ty + i) * R + r0 + tx] = f2bf(tile[tx][ty + i]);
}

// ---- V transpose: qkv V-section (t-major) -> Vt[b][h][d][t] (key-major) ----
__global__ __launch_bounds__(256) void k_vt(const ushort_t* __restrict__ qkv,
                                            ushort_t* __restrict__ vt) {
  __shared__ ushort_t tl[64][72];
  const int T = 2048, C3 = 3072;
  const int t0 = blockIdx.x * 64, h = blockIdx.y, b = blockIdx.z;
  const int r = threadIdx.x >> 4;         // 0..15
  const int c4 = (threadIdx.x & 15) * 4;  // 0..60
  const ushort_t* src = qkv + (size_t)(b * T + t0) * C3 + 2048 + h * 64;
#pragma unroll
  for (int p = 0; p < 4; p++) {
    const int row = p * 16 + r;
    *(short4*)&tl[row][c4] = *(const short4*)(src + (size_t)row * C3 + c4);
  }
  __syncthreads();
  ushort_t* dst = vt + (size_t)((b * 16 + h) * 64) * T + t0;
#pragma unroll
  for (int p = 0; p < 4; p++) {
    const int d = p * 16 + r;
    short4 o;
    o.x = (short)tl[c4 + 0][d];
    o.y = (short)tl[c4 + 1][d];
    o.z = (short)tl[c4 + 2][d];
    o.w = (short)tl[c4 + 3][d];
    *(short4*)(dst + (size_t)d * T + c4) = o;
  }
}

// ---------------- bf16 GEMM: C[M,N] = A[M,K] * Bt[N,K]^T -------------------
template <bool OUT_BF16>
__global__ __launch_bounds__(256) void k_gemm_bt(const ushort_t* __restrict__ A,
                                                 const ushort_t* __restrict__ Bt,
                                                 void* __restrict__ Cout,
                                                 int N, int K) {
  __shared__ ushort_t As[128 * 64];
  __shared__ ushort_t Bs[128 * 64];
  const int tid = threadIdx.x;
  const int wave = tid >> 6, lane = tid & 63;
  const int c = lane & 15, g = lane >> 4;
  const int wm = wave >> 1, wn = wave & 1;
  const int bx = blockIdx.x, by = blockIdx.y;

  f32x4 acc[4][4];
#pragma unroll
  for (int m = 0; m < 4; m++)
#pragma unroll
    for (int n = 0; n < 4; n++) acc[m][n] = (f32x4){0.f, 0.f, 0.f, 0.f};

  for (int k0 = 0; k0 < K; k0 += 64) {
#pragma unroll
    for (int i = 0; i < 4; i++) {
      const int flat = i * 256 + tid;
      const ushort_t* srcA = A + (size_t)(by * 128 + (flat >> 3)) * K + k0 + (flat & 7) * 8;
      const ushort_t* srcB = Bt + (size_t)(bx * 128 + (flat >> 3)) * K + k0 + (flat & 7) * 8;
      const int ldsoff = (i * 256 + wave * 64) * 16;
      __builtin_amdgcn_global_load_lds((const AS1 void*)srcA,
                                       (AS3 void*)((char*)As + ldsoff), 16, 0, 0);
      __builtin_amdgcn_global_load_lds((const AS1 void*)srcB,
                                       (AS3 void*)((char*)Bs + ldsoff), 16, 0, 0);
    }
    __syncthreads();
#pragma unroll
    for (int kk = 0; kk < 2; kk++) {
      short8 af[4], bfr[4];
#pragma unroll
      for (int m = 0; m < 4; m++)
        af[m] = *(const short8*)(As + (wm * 64 + m * 16 + c) * 64 + kk * 32 + g * 8);
#pragma unroll
      for (int n = 0; n < 4; n++)
        bfr[n] = *(const short8*)(Bs + (wn * 64 + n * 16 + c) * 64 + kk * 32 + g * 8);
#pragma unroll
      for (int m = 0; m < 4; m++)
#pragma unroll
        for (int n = 0; n < 4; n++)
          acc[m][n] = __builtin_amdgcn_mfma_f32_16x16x32_bf16(af[m], bfr[n], acc[m][n], 0, 0, 0);
    }
    __syncthreads();
  }

#pragma unroll
  for (int m = 0; m < 4; m++)
#pragma unroll
    for (int n = 0; n < 4; n++) {
      const int col = bx * 128 + wn * 64 + n * 16 + c;
#pragma unroll
      for (int r = 0; r < 4; r++) {
        const int row = by * 128 + wm * 64 + m * 16 + g * 4 + r;
        if (OUT_BF16)
          ((ushort_t*)Cout)[(size_t)row * N + col] = f2bf(acc[m][n][r]);
        else
          ((float*)Cout)[(size_t)row * N + col] = acc[m][n][r];
      }
    }
}

// ---------------- flash attention, causal, hs=64 ----------------------------
// Grid (16, H, B): block = 128 q-rows (4 waves x 32), 64-key tiles.
// K/V tiles LDS-staged (global_load_lds, XOR-swizzled), double-buffered.
// S^T = K*Q^T, y^T = V^T*P^T: softmax state lives at q = lane&15, no
// cross-lane for max/sum/rescale beyond 2 shfl_xor per fragment.

// Stage one 64x64 bf16 tile pair (K rows t-major, Vt rows d-major) into LDS.
// LDS layout: row r (128B) holds global 16B-block u at slot u^(r&7)
// (involution), so the ds_read side applies byte ^= ((r&7)<<4).
__device__ __forceinline__ void stage_kv(const ushort_t* __restrict__ Kp,
                                         const ushort_t* __restrict__ Vt,
                                         ushort_t* Kl, ushort_t* Vl,
                                         int kb, int wave, int lane) {
  const int C3 = 3072, T = 2048;
#pragma unroll
  for (int j = 0; j < 2; j++) {
    const int rbase = wave * 16 + j * 8;
    const int r = rbase + (lane >> 3);
    const int cbg = ((lane & 7) ^ (r & 7)) << 4;  // pre-swizzled global byte col
    const int ldsbase = rbase * 128;               // + lane*16 implicit
    __builtin_amdgcn_global_load_lds(
        (const AS1 void*)(Kp + (size_t)(kb + r) * C3 + (cbg >> 1)),
        (AS3 void*)((char*)Kl + ldsbase), 16, 0, 0);
    __builtin_amdgcn_global_load_lds(
        (const AS1 void*)(Vt + (size_t)r * T + kb + (cbg >> 1)),
        (AS3 void*)((char*)Vl + ldsbase), 16, 0, 0);
  }
}

__global__ __launch_bounds__(256, 2) void k_attn(const ushort_t* __restrict__ qkv,
                                                 const ushort_t* __restrict__ vt,
                                                 ushort_t* __restrict__ y) {
  const int T = 2048, C3 = 3072, Cc = 1024;
  __shared__ ushort_t Kl[2][64 * 64];
  __shared__ ushort_t Vl[2][64 * 64];

  const int tid = threadIdx.x;
  const int wave = tid >> 6, lane = tid & 63;
  const int c = lane & 15, g = lane >> 4;
  const int b = blockIdx.z, h = blockIdx.y;
  const int qi = 15 - blockIdx.x;  // heaviest causal blocks dispatch first
  const int qbase = qi * 128 + wave * 32;

  const size_t base = (size_t)b * T * C3 + h * 64;
  const ushort_t* Q = qkv + base;
  const ushort_t* Kp = qkv + base + 1024;
  const ushort_t* Vt = vt + (size_t)((b * 16 + h) * 64) * T;

  const float KS = 0.125f * 1.44269504f;  // 1/sqrt(64) * log2(e)

  // Q^T B-fragments: lane holds Q[qbase+f*16+c][kk*32+g*8 .. +8]
  short8 qf[2][2];
#pragma unroll
  for (int f = 0; f < 2; f++) {
    const ushort_t* qp = Q + (size_t)(qbase + f * 16 + c) * C3 + g * 8;
    qf[f][0] = *(const short8*)qp;
    qf[f][1] = *(const short8*)(qp + 32);
  }

  f32x4 yacc[2][4];
#pragma unroll
  for (int f = 0; f < 2; f++)
#pragma unroll
    for (int dc = 0; dc < 4; dc++) yacc[f][dc] = (f32x4){0.f, 0.f, 0.f, 0.f};
  float mx[2] = {-3.0e38f, -3.0e38f};
  float ssum[2] = {0.f, 0.f};
  const int shamt = (g & 2) * 8;

  const int nk_blk = (qi + 1) * 128;  // block-uniform trip count
  stage_kv(Kp, Vt, Kl[0], Vl[0], 0, wave, lane);
  __syncthreads();
  int cur = 0;

  for (int kb = 0; kb < nk_blk; kb += 64) {
    if (kb + 64 < nk_blk)
      stage_kv(Kp, Vt, Kl[cur ^ 1], Vl[cur ^ 1], kb + 64, wave, lane);

    if (kb < qbase + 32) {  // wave-uniform: this wave has live rows in tile
      const char* Kbuf = (const char*)Kl[cur];
      const char* Vbuf = (const char*)Vl[cur];
      unsigned pk[2][2][4];

#pragma unroll
      for (int f = 0; f < 2; f++) {
        // K A-fragments from LDS (swizzled): K[kb+sub*16+c][kk*32+g*8]
        short8 kf[4][2];
#pragma unroll
        for (int sub = 0; sub < 4; sub++) {
          const int r = sub * 16 + c;
          const int sw = (r & 7) << 4;
#pragma unroll
          for (int kk = 0; kk < 2; kk++)
            kf[sub][kk] = *(const short8*)(Kbuf + r * 128 + ((kk * 64 + g * 16) ^ sw));
        }
        f32x4 s[4];
        const f32x4 z = (f32x4){0.f, 0.f, 0.f, 0.f};
#pragma unroll
        for (int sub = 0; sub < 4; sub++) {
          s[sub] = __builtin_amdgcn_mfma_f32_16x16x32_bf16(kf[sub][0], qf[f][0], z, 0, 0, 0);
          s[sub] = __builtin_amdgcn_mfma_f32_16x16x32_bf16(kf[sub][1], qf[f][1], s[sub], 0, 0, 0);
        }

        float sv[16];
#pragma unroll
        for (int sub = 0; sub < 4; sub++)
#pragma unroll
          for (int r = 0; r < 4; r++) sv[sub * 4 + r] = s[sub][r];

        const int q = qbase + f * 16 + c;
        if (kb + 63 > qbase + f * 16) {  // diagonal: causal mask
#pragma unroll
          for (int j = 0; j < 16; j++) {
            const int key = kb + (j >> 2) * 16 + g * 4 + (j & 3);
            if (key > q) sv[j] = -3.0e38f;
          }
        }

        // online softmax at q = lane&15 (replicated over 4 lane-groups)
        float tm = sv[0];
#pragma unroll
        for (int j = 1; j < 16; j++) tm = fmaxf(tm, sv[j]);
        tm = fmaxf(tm, __shfl_xor(tm, 16));
        tm = fmaxf(tm, __shfl_xor(tm, 32));
        const float mnew = fmaxf(mx[f], tm * KS);
        const float alpha = EXP2(mx[f] - mnew);
        mx[f] = mnew;
        ssum[f] *= alpha;
#pragma unroll
        for (int dc = 0; dc < 4; dc++)
#pragma unroll
          for (int r = 0; r < 4; r++) yacc[f][dc][r] *= alpha;

        float p[16], ts = 0.f;
#pragma unroll
        for (int j = 0; j < 16; j++) {
          p[j] = EXP2(__builtin_fmaf(sv[j], KS, -mnew));
          ts += p[j];
        }
        ts += __shfl_xor(ts, 16);
        ts += __shfl_xor(ts, 32);
        ssum[f] += ts;

        // pack: pk[hh][jr] = (p[8hh+jr], p[8hh+4+jr]) -> bf16 pair
#pragma unroll
        for (int jr = 0; jr < 4; jr++) {
          pk[f][0][jr] = cvt_pk_bf16(p[jr], p[4 + jr]);
          pk[f][1][jr] = cvt_pk_bf16(p[8 + jr], p[12 + jr]);
        }
      }

      // PV: two 32-key halves; V^T A-fragment shared by both q-fragments
#pragma unroll
      for (int hh = 0; hh < 2; hh++) {
        short8 vf[4];
#pragma unroll
        for (int dc = 0; dc < 4; dc++) {
          const int r = dc * 16 + c;
          const int sw = (r & 7) << 4;
          vf[dc] = *(const short8*)(Vbuf + r * 128 + ((hh * 64 + g * 16) ^ sw));
        }
#pragma unroll
        for (int f = 0; f < 2; f++) {
          // P^T B-fragment: pf[r] = P[q=c][key = kb + hh*32 + g*8 + r]
          short8 pf;
#pragma unroll
          for (int r = 0; r < 8; r++) {
            const int G = (2 * g + (r >> 2)) & 3;
            const unsigned w = __shfl(pk[f][hh][r & 3], c | (G << 4), 64);
            pf[r] = (short)(ushort_t)(w >> shamt);
          }
#pragma unroll
          for (int dc = 0; dc < 4; dc++)
            yacc[f][dc] = __builtin_amdgcn_mfma_f32_16x16x32_bf16(vf[dc], pf, yacc[f][dc], 0, 0, 0);
        }
      }
    }

    __syncthreads();  // drains vmcnt: next tile staged, this tile's reads done
    cur ^= 1;
  }

  // normalize + packed store (short4), per q-fragment
#pragma unroll
  for (int f = 0; f < 2; f++) {
    const float inv = 1.0f / ssum[f];
    const int q = qbase + f * 16 + c;
    ushort_t* yp = y + (size_t)(b * T + q) * Cc + h * 64;
#pragma unroll
    for (int dc = 0; dc < 4; dc++) {
      short4 o;
      o.x = (short)f2bf(yacc[f][dc][0] * inv);
      o.y = (short)f2bf(yacc[f][dc][1] * inv);
      o.z = (short)f2bf(yacc[f][dc][2] * inv);
      o.w = (short)f2bf(yacc[f][dc][3] * inv);
      *(short4*)(yp + dc * 16 + g * 4) = o;
    }
  }
}

// ---------------------------------------------------------------------------
extern "C" void kernel_launch(void* const* d_in, const int* in_sizes, int n_in,
                              void* d_out, int out_size, void* d_ws, size_t ws_size,
                              hipStream_t stream) {
  const float* x = (const float*)d_in[0];     // (4, 2048, 1024)
  const float* Wat = (const float*)d_in[1];   // (1024, 3072)
  const float* Wpr = (const float*)d_in[2];   // (1024, 1024)
  float* out = (float*)d_out;                 // (4, 2048, 1024)

  const int T = 2048, B = 4, H = 16, Cc = 1024;
  const int M = B * T;  // 8192

  char* ws = (char*)d_ws;
  const size_t MB = 1024 * 1024;
  ushort_t* xb = (ushort_t*)ws;                 // 16 MB (x_bf16, then Vt)
  ushort_t* wat = (ushort_t*)(ws + 16 * MB);    // 6 MB
  ushort_t* wpt = (ushort_t*)(ws + 24 * MB);    // 2 MB
  ushort_t* qkv = (ushort_t*)(ws + 32 * MB);    // 48 MB
  ushort_t* yb = (ushort_t*)(ws + 80 * MB);     // 16 MB
  ushort_t* vtb = xb;                           // reuse after GEMM1

  // 1. convert inputs to bf16 (weights transposed to [N][K])
  k_f32_to_bf16<<<dim3((M * Cc) / (8 * 256)), 256, 0, stream>>>(x, xb);
  k_transpose_bf16<<<dim3(3072 / 32, 1024 / 32), 256, 0, stream>>>(Wat, wat, 1024, 3072);
  k_transpose_bf16<<<dim3(1024 / 32, 1024 / 32), 256, 0, stream>>>(Wpr, wpt, 1024, 1024);

  // 2. qkv = x @ W_attn   (8192 x 3072)
  k_gemm_bt<true><<<dim3(3072 / 128, M / 128), 256, 0, stream>>>(xb, wat, qkv, 3072, 1024);

  // 3. V -> Vt[b][h][d][t]  (xb region is dead now)
  k_vt<<<dim3(T / 64, H, B), 256, 0, stream>>>(qkv, vtb);

  // 4. causal flash attention -> y (8192 x 1024 bf16)
  k_attn<<<dim3(16, H, B), 256, 0, stream>>>(qkv, vtb, yb);

  // 5. out = y @ W_proj   (8192 x 1024, fp32)
  k_gemm_bt<false><<<dim3(1024 / 128, M / 128), 256, 0, stream>>>(yb, wpt, out, 1024, 1024);
}